// Round 6
// baseline (743.766 us; speedup 1.0000x reference)
//
#include <hip/hip_runtime.h>

typedef unsigned char u8;
typedef unsigned short u16;
typedef unsigned int u32;
typedef long i64;
typedef __attribute__((ext_vector_type(2))) long long2v;
typedef __attribute__((ext_vector_type(4))) float floatx4;

#define LOG2PI_F 1.8378770664093453f

// ---------- helpers ----------
__device__ __forceinline__ u8 f2fp8(float f) {
  int p = __builtin_amdgcn_cvt_pk_fp8_f32(f, f, 0, false);
  return (u8)(p & 0xff);
}
__device__ __forceinline__ u32 pk4fp8(float a, float b, float c, float d) {
  int lo = __builtin_amdgcn_cvt_pk_fp8_f32(a, b, 0, false);
  int v  = __builtin_amdgcn_cvt_pk_fp8_f32(c, d, lo, true);
  return (u32)v;
}
// unpack 4 fp8 bytes -> 4 floats (selector must be a literal constant)
__device__ __forceinline__ void up4fp8(u32 pk, float* o) {
  o[0] = __builtin_amdgcn_cvt_f32_fp8(pk, 0);
  o[1] = __builtin_amdgcn_cvt_f32_fp8(pk, 1);
  o[2] = __builtin_amdgcn_cvt_f32_fp8(pk, 2);
  o[3] = __builtin_amdgcn_cvt_f32_fp8(pk, 3);
}
__device__ __forceinline__ void llds16(const void* g, void* l) {
  __builtin_amdgcn_global_load_lds(
      (const __attribute__((address_space(1))) u32*)g,
      (__attribute__((address_space(3))) u32*)l, 16, 0, 0);
}
// K-storage permutation: per 64-k group, octet order O0,O4,O1,O5,O2,O6,O3,O7
// so 16B chunk q holds octets (q, q+4) = the (h0,h1) pair for MFMA quad q.
__device__ __forceinline__ u32 permk(u32 k) {
  u32 g = k & ~63u, o = (k >> 3) & 7u, r = k & 7u;
  u32 po = ((o & 3u) << 1) | (o >> 2);
  return g | (po << 3) | r;
}

// Scales (powers of 2; keep e4m3 out of subnormals):
//   x*16, weights*256, tanh-activations*64, z*16. Inverses folded into epilogues.
#define INV_4096  2.44140625e-4f
#define INV_16384 6.103515625e-5f

// ---------- packing kernels ----------
__global__ void pack_xb(const float* __restrict__ in, u32* __restrict__ out, int n4) {
  int i = blockIdx.x * 256 + threadIdx.x;
  if (i >= n4) return;
  const float4 v = ((const float4*)in)[i];
  int row = i >> 7;                    // D/4 = 128
  int k = (i & 127) << 2;
  int kp = permk(k);                   // float4 stays inside one octet
  out[(row << 7) + (kp >> 2)] = pk4fp8(v.x * 16.f, v.y * 16.f, v.z * 16.f, v.w * 16.f);
}

// W [K][N] fp32 -> Wt [N][permk(K)] fp8 (*256)
__global__ void pack_wt(const float* __restrict__ W, u8* __restrict__ Wt, int K, int N) {
  int idx = blockIdx.x * 256 + threadIdx.x;
  if (idx >= K * N) return;
  int k = idx / N, n = idx - k * N;
  Wt[(size_t)n * K + permk(k)] = f2fp8(W[idx] * 256.f);
}

// W1 [K][N1], W2 [K][N2] fp32 -> Wt [(N1+N2)][permk(K)] fp8 (*256)
__global__ void pack_wt2(const float* __restrict__ W1, const float* __restrict__ W2,
                         u8* __restrict__ Wt, int K, int N1, int N2) {
  int idx = blockIdx.x * 256 + threadIdx.x;
  if (idx >= (N1 + N2) * K) return;
  int n = idx / K, k = idx - n * K;
  float v = (n < N1) ? W1[(size_t)k * N1 + n] : W2[(size_t)k * N2 + (n - N1)];
  Wt[(size_t)n * K + permk(k)] = f2fp8(v * 256.f);
}

// all four bias vectors in one launch (3200 elements)
__global__ void catb(const float* __restrict__ beh, const float* __restrict__ bem,
                     const float* __restrict__ bel, const float* __restrict__ bdhi,
                     const float* __restrict__ bdm, const float* __restrict__ bdl,
                     float* __restrict__ bh, float* __restrict__ bz,
                     float* __restrict__ bdh, float* __restrict__ bdx) {
  int i = blockIdx.x * 256 + threadIdx.x;
  if (i < 1024) bh[i] = beh[i];
  else if (i < 1152) { int j = i - 1024; bz[j] = (j < 64) ? bem[j] : bel[j - 64]; }
  else if (i < 2176) { int j = i - 1152; bdh[j] = bdhi[j]; }
  else if (i < 3200) { int j = i - 2176; bdx[j] = (j < 512) ? bdm[j] : bdl[j - 512]; }
}

// ---------- fp8 MFMA GEMM: C = tanh(A @ Bt^T * inv + bias) -> fp8*outs ----------
// A: [M][K] fp8 (K permuted), Bt: [N][K] fp8 (K permuted), bias: [N] f32. BK=64.
__global__ __launch_bounds__(256) void gemm_bt(
    const u8* __restrict__ A, const u8* __restrict__ Bt,
    const float* __restrict__ bias, u8* __restrict__ Cv,
    float inv, float outs, int M, int N, int K) {
  __shared__ __align__(16) u8 As[128 * 64];
  __shared__ __align__(16) u8 Bs[128 * 64];
  const int t = threadIdx.x;
  const int wave = t >> 6, lane = t & 63;
  const int quad = lane >> 4, l16 = lane & 15;
  const int bm = blockIdx.y * 128, bn = blockIdx.x * 128;
  const int wm = (wave >> 1) * 64, wn = (wave & 1) * 64;

  floatx4 acc[4][4];
#pragma unroll
  for (int i = 0; i < 4; ++i)
#pragma unroll
    for (int j = 0; j < 4; ++j) acc[i][j] = (floatx4){0.f, 0.f, 0.f, 0.f};

  for (int kt = 0; kt < K; kt += 64) {
#pragma unroll
    for (int i = 0; i < 2; ++i) {
      int c = i * 256 + t;
      int r = c >> 2, kcS = c & 3;
      int kc = kcS ^ ((r >> 1) & 3);
      llds16(A + (size_t)(bm + r) * K + kt + kc * 16, &As[c * 16]);
      llds16(Bt + (size_t)(bn + r) * K + kt + kc * 16, &Bs[c * 16]);
    }
    __builtin_amdgcn_s_waitcnt(0);
    __syncthreads();

    long2v a2[4], b2[4];
#pragma unroll
    for (int mi = 0; mi < 4; ++mi) {
      int m = wm + mi * 16 + l16;
      a2[mi] = *(const long2v*)&As[(4 * m + (quad ^ ((m >> 1) & 3))) * 16];
    }
#pragma unroll
    for (int ni = 0; ni < 4; ++ni) {
      int n = wn + ni * 16 + l16;
      b2[ni] = *(const long2v*)&Bs[(4 * n + (quad ^ ((n >> 1) & 3))) * 16];
    }
#pragma unroll
    for (int h = 0; h < 2; ++h)
#pragma unroll
      for (int mi = 0; mi < 4; ++mi)
#pragma unroll
        for (int ni = 0; ni < 4; ++ni)
          acc[mi][ni] = __builtin_amdgcn_mfma_f32_16x16x32_fp8_fp8(
              a2[mi][h], b2[ni][h], acc[mi][ni], 0, 0, 0);
    __syncthreads();
  }

  // epilogue: D[row=quad*4+r][col=lane&15]
#pragma unroll
  for (int ni = 0; ni < 4; ++ni) {
    int col = bn + wn + ni * 16 + l16;
    float bv = bias[col];
#pragma unroll
    for (int mi = 0; mi < 4; ++mi) {
#pragma unroll
      for (int r = 0; r < 4; ++r) {
        int row = bm + wm + mi * 16 + quad * 4 + r;
        float v = acc[mi][ni][r] * inv + bv;
        Cv[(size_t)row * N + permk(col)] = f2fp8(tanhf(v) * outs);
      }
    }
  }
}

// ---------- fused GEMM23 + reparameterise + KL (fp8) ----------
__global__ __launch_bounds__(256) void gemm_z(
    const u8* __restrict__ A, const u8* __restrict__ Bt,
    const float* __restrict__ bias, const float* __restrict__ eps,
    u8* __restrict__ z, float* __restrict__ accp, int M, int K) {
  __shared__ __align__(16) u8 As[128 * 64];
  __shared__ __align__(16) u8 Bs[128 * 64];
  __shared__ float sexp[128 * 64];   // exp(0.5*lv) staging [row][col]
  const int t = threadIdx.x;
  const int wave = t >> 6, lane = t & 63;
  const int quad = lane >> 4, l16 = lane & 15;
  const int bm = blockIdx.y * 128;
  const int wm = (wave >> 1) * 64, wn = (wave & 1) * 64;

  floatx4 acc[4][4];
#pragma unroll
  for (int i = 0; i < 4; ++i)
#pragma unroll
    for (int j = 0; j < 4; ++j) acc[i][j] = (floatx4){0.f, 0.f, 0.f, 0.f};

  for (int kt = 0; kt < K; kt += 64) {
#pragma unroll
    for (int i = 0; i < 2; ++i) {
      int c = i * 256 + t;
      int r = c >> 2, kcS = c & 3;
      int kc = kcS ^ ((r >> 1) & 3);
      llds16(A + (size_t)(bm + r) * K + kt + kc * 16, &As[c * 16]);
      llds16(Bt + (size_t)r * K + kt + kc * 16, &Bs[c * 16]);
    }
    __builtin_amdgcn_s_waitcnt(0);
    __syncthreads();

    long2v a2[4], b2[4];
#pragma unroll
    for (int mi = 0; mi < 4; ++mi) {
      int m = wm + mi * 16 + l16;
      a2[mi] = *(const long2v*)&As[(4 * m + (quad ^ ((m >> 1) & 3))) * 16];
    }
#pragma unroll
    for (int ni = 0; ni < 4; ++ni) {
      int n = wn + ni * 16 + l16;
      b2[ni] = *(const long2v*)&Bs[(4 * n + (quad ^ ((n >> 1) & 3))) * 16];
    }
#pragma unroll
    for (int h = 0; h < 2; ++h)
#pragma unroll
      for (int mi = 0; mi < 4; ++mi)
#pragma unroll
        for (int ni = 0; ni < 4; ++ni)
          acc[mi][ni] = __builtin_amdgcn_mfma_f32_16x16x32_fp8_fp8(
              a2[mi][h], b2[ni][h], acc[mi][ni], 0, 0, 0);
    __syncthreads();
  }

  const bool is_lv = (wave & 1);
  float kl = 0.f;
#pragma unroll
  for (int ni = 0; ni < 4; ++ni) {
    int col = wn + ni * 16 + l16;            // 0..127
    float bv = bias[col];
#pragma unroll
    for (int mi = 0; mi < 4; ++mi) {
#pragma unroll
      for (int r = 0; r < 4; ++r) {
        int row = wm + mi * 16 + quad * 4 + r;   // 0..127 local
        float v = acc[mi][ni][r] * INV_16384 + bv;
        if (is_lv) {
          kl += 1.0f + v - __expf(v);
          sexp[row * 64 + (col - 64)] = __expf(0.5f * v);
        } else {
          kl -= v * v;
        }
      }
    }
  }
  __syncthreads();
  if (!is_lv) {
#pragma unroll
    for (int ni = 0; ni < 4; ++ni) {
      int col = wn + ni * 16 + l16;          // 0..63
      float bv = bias[col];
#pragma unroll
      for (int mi = 0; mi < 4; ++mi) {
#pragma unroll
        for (int r = 0; r < 4; ++r) {
          int row = wm + mi * 16 + quad * 4 + r;
          float mu = acc[mi][ni][r] * INV_16384 + bv;
          size_t grow = (size_t)(bm + row);
          float ep = eps[grow * 64 + col];
          z[grow * 64 + permk(col)] = f2fp8((mu + sexp[row * 64 + col] * ep) * 16.f);
        }
      }
    }
  }
  kl *= 0.5f;
  for (int off = 32; off > 0; off >>= 1) kl += __shfl_xor(kl, off, 64);
  __shared__ float s4[4];
  if (lane == 0) s4[wave] = kl;
  __syncthreads();
  if (t == 0) atomicAdd(accp, s4[0] + s4[1] + s4[2] + s4[3]);
}

// ---------- fused GEMM56 + softmax + diag-Gaussian log-likelihood ----------
// One block owns a 128-row x 1024-col strip. A staged in LDS; B (weights, L2-hot)
// loaded straight to VGPR fragments. nt 0..3: logits -> e^logit stored fp8 in
// Plds[col][row] (pad 136 => <=2-way LDS aliasing), fp32 row-sums in registers.
// nt 4..7: lv tiles; read back p = e^lgt / s, read x, accumulate T.
// accp += Sum_rows( -0.5 * Sum_j [lv + (x-p)^2 e^-lv] )   (LOG2PI added in fin)
#define PPAD 136
__global__ __launch_bounds__(256) void gemm_lik(
    const u8* __restrict__ A, const u8* __restrict__ Bt,
    const float* __restrict__ bias, const float* __restrict__ x,
    float* __restrict__ accp, int M, int K) {
  __shared__ __align__(16) u8 As[128 * 64];       // 8 KB
  __shared__ __align__(16) u8 Plds[512 * PPAD];   // 68 KB: e^logit fp8, [col][row]
  __shared__ float srow[128 * 2];                 // per-row softmax-denominator slots
  __shared__ float s4[4];
  const int t = threadIdx.x;
  const int wave = t >> 6, lane = t & 63;
  const int quad = lane >> 4, l16 = lane & 15;
  const int bm = blockIdx.x * 128;
  const int wm = (wave >> 1) * 64, wn = (wave & 1) * 64;

  float rsum[16];
#pragma unroll
  for (int i = 0; i < 16; ++i) rsum[i] = 0.f;
  float invs[16];
  float wT = 0.f;

  for (int nt = 0; nt < 8; ++nt) {
    floatx4 acc[4][4];
#pragma unroll
    for (int i = 0; i < 4; ++i)
#pragma unroll
      for (int j = 0; j < 4; ++j) acc[i][j] = (floatx4){0.f, 0.f, 0.f, 0.f};

    for (int kt = 0; kt < K; kt += 64) {
      // stage A tile (8 KB): 512 chunks / 256 threads
#pragma unroll
      for (int i = 0; i < 2; ++i) {
        int c = i * 256 + t;
        int r = c >> 2, kcS = c & 3;
        int kc = kcS ^ ((r >> 1) & 3);
        llds16(A + (size_t)(bm + r) * K + kt + kc * 16, &As[c * 16]);
      }
      // B fragments straight from global (rows are permk'd: chunk q = octets q,q+4)
      long2v b2[4];
#pragma unroll
      for (int ni = 0; ni < 4; ++ni) {
        int n = nt * 128 + wn + ni * 16 + l16;
        b2[ni] = *(const long2v*)(Bt + (size_t)n * K + kt + quad * 16);
      }
      __builtin_amdgcn_s_waitcnt(0);
      __syncthreads();

      long2v a2[4];
#pragma unroll
      for (int mi = 0; mi < 4; ++mi) {
        int m = wm + mi * 16 + l16;
        a2[mi] = *(const long2v*)&As[(4 * m + (quad ^ ((m >> 1) & 3))) * 16];
      }
#pragma unroll
      for (int h = 0; h < 2; ++h)
#pragma unroll
        for (int mi = 0; mi < 4; ++mi)
#pragma unroll
          for (int ni = 0; ni < 4; ++ni)
            acc[mi][ni] = __builtin_amdgcn_mfma_f32_16x16x32_fp8_fp8(
                a2[mi][h], b2[ni][h], acc[mi][ni], 0, 0, 0);
      __syncthreads();
    }

    if (nt < 4) {
      // logits tile: store e^logit (fp8), accumulate fp32 row-sums
#pragma unroll
      for (int ni = 0; ni < 4; ++ni) {
        int col = nt * 128 + wn + ni * 16 + l16;   // 0..511
        float bv = bias[col];
#pragma unroll
        for (int mi = 0; mi < 4; ++mi) {
          int rowb = wm + mi * 16 + quad * 4;
          float ev[4];
#pragma unroll
          for (int r = 0; r < 4; ++r) {
            float v = acc[mi][ni][r] * INV_16384 + bv;   // |logit| <~ 1.5: no max needed
            ev[r] = __expf(v);
            rsum[mi * 4 + r] += ev[r];
          }
          *(u32*)&Plds[(size_t)col * PPAD + rowb] = pk4fp8(ev[0], ev[1], ev[2], ev[3]);
        }
      }
      if (nt == 3) {
        // reduce rsum across the 16 l16-lanes (masks 1,2,4,8 stay inside the quad)
#pragma unroll
        for (int i = 0; i < 16; ++i) {
          rsum[i] += __shfl_xor(rsum[i], 1, 64);
          rsum[i] += __shfl_xor(rsum[i], 2, 64);
          rsum[i] += __shfl_xor(rsum[i], 4, 64);
          rsum[i] += __shfl_xor(rsum[i], 8, 64);
        }
        if (l16 == 0) {
#pragma unroll
          for (int mi = 0; mi < 4; ++mi)
#pragma unroll
            for (int r = 0; r < 4; ++r)
              srow[(wm + mi * 16 + quad * 4 + r) * 2 + (wave & 1)] = rsum[mi * 4 + r];
        }
        __syncthreads();
#pragma unroll
        for (int mi = 0; mi < 4; ++mi)
#pragma unroll
          for (int r = 0; r < 4; ++r) {
            int row = wm + mi * 16 + quad * 4 + r;
            invs[mi * 4 + r] = 1.0f / (srow[row * 2] + srow[row * 2 + 1]);
          }
      }
    } else {
      // lv tile: T += lv + (x - p)^2 * e^-lv
#pragma unroll
      for (int ni = 0; ni < 4; ++ni) {
        int col = nt * 128 + wn + ni * 16 + l16;   // 512..1023
        int colx = col - 512;
        float bv = bias[col];
#pragma unroll
        for (int mi = 0; mi < 4; ++mi) {
          int rowb = wm + mi * 16 + quad * 4;
          u32 pk = *(const u32*)&Plds[(size_t)colx * PPAD + rowb];
          float pv[4];
          up4fp8(pk, pv);
#pragma unroll
          for (int r = 0; r < 4; ++r) {
            float lv = acc[mi][ni][r] * INV_16384 + bv;
            float p = pv[r] * invs[mi * 4 + r];
            float xv = x[(size_t)(bm + rowb + r) * 512 + colx];
            float d = xv - p;
            wT += lv + d * d * __expf(-lv);
          }
        }
      }
    }
  }

  // block reduction of likelihood partial
  for (int off = 32; off > 0; off >>= 1) wT += __shfl_xor(wT, off, 64);
  if (lane == 0) s4[wave] = wT;
  __syncthreads();
  if (t == 0) atomicAdd(accp, -0.5f * (s4[0] + s4[1] + s4[2] + s4[3]));
}

__global__ void fin_kernel(const float* __restrict__ acc, float* __restrict__ out) {
  out[0] = acc[0] * (1.0f / 65536.0f) - 256.0f * LOG2PI_F;
}

// ---------- launch ----------
extern "C" void kernel_launch(void* const* d_in, const int* in_sizes, int n_in,
                              void* d_out, int out_size, void* d_ws, size_t ws_size,
                              hipStream_t stream) {
  const int B = 65536, D = 512, H = 1024, L = 64;
  const float* x       = (const float*)d_in[0];
  const float* eps     = (const float*)d_in[1];
  const float* W_enc_h = (const float*)d_in[2];
  const float* b_enc_h = (const float*)d_in[3];
  const float* W_enc_mu= (const float*)d_in[4];
  const float* b_enc_mu= (const float*)d_in[5];
  const float* W_enc_lv= (const float*)d_in[6];
  const float* b_enc_lv= (const float*)d_in[7];
  const float* W_dec_h = (const float*)d_in[8];
  const float* b_dec_h = (const float*)d_in[9];
  const float* W_dec_mu= (const float*)d_in[10];
  const float* b_dec_mu= (const float*)d_in[11];
  const float* W_dec_lv= (const float*)d_in[12];
  const float* b_dec_lv= (const float*)d_in[13];

  char* ws = (char*)d_ws;
  // weights (fp8) / bias / acc block
  u8*   Wt_eh  = (u8*)(ws + 0);             // [1024][512]  512K
  u8*   Wt_z   = (u8*)(ws + 524288);        // [128][1024]  128K
  u8*   Wt_dh  = (u8*)(ws + 655360);        // [1024][64]    64K
  u8*   Wt_dx  = (u8*)(ws + 720896);        // [1024][1024]   1M
  float* bh    = (float*)(ws + 2097152);    // [1024]
  float* bz    = (float*)(ws + 2101248);    // [128]
  float* bdh   = (float*)(ws + 2105344);    // [1024]
  float* bdx   = (float*)(ws + 2109440);    // [1024]
  float* acc   = (float*)(ws + 2113536);    // [1]
  // big regions (peak 108 MB)
  u8*   hbuf   = (u8*)(ws + 4194304);       // [B][1024] fp8: h then hd (64MB)
  u8*   xb     = (u8*)(ws + 71303168);      // [B][512] fp8 (32MB, dead after GEMM1)
  u8*   zbuf   = (u8*)(ws + 104857600);     // [B][64] fp8 (4MB, dead after GEMM4)

  (void)hipMemsetAsync(acc, 0, 256, stream);

  // ---- packing ----
  pack_xb<<<(B * D / 4 + 255) / 256, 256, 0, stream>>>(x, (u32*)xb, B * D / 4);
  pack_wt<<<(D * H + 255) / 256, 256, 0, stream>>>(W_enc_h, Wt_eh, D, H);
  pack_wt2<<<(H * 2 * L + 255) / 256, 256, 0, stream>>>(W_enc_mu, W_enc_lv, Wt_z, H, L, L);
  pack_wt<<<(L * H + 255) / 256, 256, 0, stream>>>(W_dec_h, Wt_dh, L, H);
  pack_wt2<<<(H * 2 * D + 255) / 256, 256, 0, stream>>>(W_dec_mu, W_dec_lv, Wt_dx, H, D, D);
  catb<<<13, 256, 0, stream>>>(b_enc_h, b_enc_mu, b_enc_lv, b_dec_h, b_dec_mu, b_dec_lv,
                               bh, bz, bdh, bdx);

  // ---- encoder: h = tanh(x @ W_enc_h + b), h stored fp8*64, K-permuted ----
  gemm_bt<<<dim3(H / 128, B / 128), 256, 0, stream>>>(
      xb, Wt_eh, bh, hbuf, INV_4096, 64.f, B, H, D);
  // ---- fused: mu|lv = h @ Wt_z + b ; z = mu + exp(.5 lv) eps (fp8*16) ; KL ----
  gemm_z<<<dim3(1, B / 128), 256, 0, stream>>>(hbuf, Wt_z, bz, eps, zbuf, acc, B, H);
  // ---- decoder hidden: hd = tanh(z @ W_dec_h + b), fp8*64 (overwrites hbuf) ----
  gemm_bt<<<dim3(H / 128, B / 128), 256, 0, stream>>>(
      zbuf, Wt_dh, bdh, hbuf, INV_4096, 64.f, B, H, L);
  // ---- fused: logits|lv_x GEMM + softmax + Gaussian log-likelihood ----
  gemm_lik<<<B / 128, 256, 0, stream>>>(hbuf, Wt_dx, bdx, x, acc, B, H);
  // ---- finalize mean ----
  fin_kernel<<<1, 1, 0, stream>>>(acc, (float*)d_out);
}